// Round 1
// baseline (923.991 us; speedup 1.0000x reference)
//
#include <hip/hip_runtime.h>

// 3-layer GCN: 2 -> 16 -> 16 -> 1, N=250000 nodes, E=4000000 edges.
// deg/dinv computed once; per layer: dense transform (W in LDS) + edge scatter.

constexpr int F = 16;

__global__ void k_deg_init(float* __restrict__ deg, int n) {
    int i = blockIdx.x * blockDim.x + threadIdx.x;
    int stride = gridDim.x * blockDim.x;
    for (; i < n; i += stride) deg[i] = 1.0f;   // self-loop
}

__global__ void k_deg_accum(const int* __restrict__ dst, float* __restrict__ deg, int E) {
    int i = blockIdx.x * blockDim.x + threadIdx.x;
    int stride = gridDim.x * blockDim.x;
    for (; i < E; i += stride) atomicAdd(&deg[dst[i]], 1.0f);
}

__global__ void k_dinv(float* __restrict__ deg, int n) {
    int i = blockIdx.x * blockDim.x + threadIdx.x;
    int stride = gridDim.x * blockDim.x;
    for (; i < n; i += stride) deg[i] = rsqrtf(deg[i]);   // in place: deg -> dinv
}

// xw = x @ W1   (x: [n,2], W1: [2,16])
__global__ void k_l1_transform(const float* __restrict__ x, const float* __restrict__ W1,
                               float* __restrict__ xw, int n) {
    __shared__ float sW[32];
    if (threadIdx.x < 32) sW[threadIdx.x] = W1[threadIdx.x];
    __syncthreads();
    int i = blockIdx.x * blockDim.x + threadIdx.x;
    int stride = gridDim.x * blockDim.x;
    for (; i < n; i += stride) {
        float2 xv = reinterpret_cast<const float2*>(x)[i];
        float4* orow = reinterpret_cast<float4*>(xw + (size_t)i * F);
#pragma unroll
        for (int q = 0; q < 4; ++q) {
            float4 o;
            o.x = xv.x * sW[4*q+0] + xv.y * sW[16 + 4*q+0];
            o.y = xv.x * sW[4*q+1] + xv.y * sW[16 + 4*q+1];
            o.z = xv.x * sW[4*q+2] + xv.y * sW[16 + 4*q+2];
            o.w = xv.x * sW[4*q+3] + xv.y * sW[16 + 4*q+3];
            orow[q] = o;
        }
    }
}

// agg[dst] += dinv[src]*dinv[dst] * xw[src]   (16 features, 16 lanes per edge)
__global__ void k_scatter16(const int* __restrict__ src, const int* __restrict__ dst,
                            const float* __restrict__ dinv, const float* __restrict__ xw,
                            float* __restrict__ agg, int E) {
    long long t = (long long)blockIdx.x * blockDim.x + threadIdx.x;
    long long stride = (long long)gridDim.x * blockDim.x;
    long long total = (long long)E * F;
    for (; t < total; t += stride) {
        int e = (int)(t >> 4);
        int j = (int)(t & 15);
        int s = src[e], d = dst[e];
        float nv = dinv[s] * dinv[d];
        atomicAdd(&agg[(size_t)d * F + j], nv * xw[(size_t)s * F + j]);
    }
}

// h = relu(agg + dinv^2 * xw + b); xw (in place) = h @ W (16x16)
__global__ void k_finish_transform16(const float* __restrict__ agg, const float* __restrict__ dinv,
                                     const float* __restrict__ b, const float* __restrict__ W,
                                     float* __restrict__ xw, int n) {
    __shared__ float sW[256];
    __shared__ float sb[16];
    sW[threadIdx.x] = W[threadIdx.x];               // blockDim.x == 256
    if (threadIdx.x < 16) sb[threadIdx.x] = b[threadIdx.x];
    __syncthreads();
    int i = blockIdx.x * blockDim.x + threadIdx.x;
    int stride = gridDim.x * blockDim.x;
    for (; i < n; i += stride) {
        float di = dinv[i];
        float di2 = di * di;
        float h[16];
        const float4* arow = reinterpret_cast<const float4*>(agg + (size_t)i * F);
        float4* xrow = reinterpret_cast<float4*>(xw + (size_t)i * F);
#pragma unroll
        for (int q = 0; q < 4; ++q) {
            float4 a = arow[q];
            float4 xv = xrow[q];
            h[4*q+0] = fmaxf(a.x + di2 * xv.x + sb[4*q+0], 0.0f);
            h[4*q+1] = fmaxf(a.y + di2 * xv.y + sb[4*q+1], 0.0f);
            h[4*q+2] = fmaxf(a.z + di2 * xv.z + sb[4*q+2], 0.0f);
            h[4*q+3] = fmaxf(a.w + di2 * xv.w + sb[4*q+3], 0.0f);
        }
#pragma unroll
        for (int q = 0; q < 4; ++q) {
            float4 o = make_float4(0.f, 0.f, 0.f, 0.f);
#pragma unroll
            for (int j = 0; j < 16; ++j) {
                float hj = h[j];
                o.x += hj * sW[j*16 + 4*q+0];
                o.y += hj * sW[j*16 + 4*q+1];
                o.z += hj * sW[j*16 + 4*q+2];
                o.w += hj * sW[j*16 + 4*q+3];
            }
            xrow[q] = o;
        }
    }
}

// h = relu(agg + dinv^2 * xw + b2); xw3 = h @ W3 (16x1)
__global__ void k_finish_transform1(const float* __restrict__ agg, const float* __restrict__ dinv,
                                    const float* __restrict__ b, const float* __restrict__ W3,
                                    const float* __restrict__ xw, float* __restrict__ xw3, int n) {
    __shared__ float sW[16];
    __shared__ float sb[16];
    if (threadIdx.x < 16) { sW[threadIdx.x] = W3[threadIdx.x]; sb[threadIdx.x] = b[threadIdx.x]; }
    __syncthreads();
    int i = blockIdx.x * blockDim.x + threadIdx.x;
    int stride = gridDim.x * blockDim.x;
    for (; i < n; i += stride) {
        float di = dinv[i];
        float di2 = di * di;
        const float4* arow = reinterpret_cast<const float4*>(agg + (size_t)i * F);
        const float4* xrow = reinterpret_cast<const float4*>(xw + (size_t)i * F);
        float acc = 0.0f;
#pragma unroll
        for (int q = 0; q < 4; ++q) {
            float4 a = arow[q];
            float4 xv = xrow[q];
            acc += fmaxf(a.x + di2 * xv.x + sb[4*q+0], 0.0f) * sW[4*q+0];
            acc += fmaxf(a.y + di2 * xv.y + sb[4*q+1], 0.0f) * sW[4*q+1];
            acc += fmaxf(a.z + di2 * xv.z + sb[4*q+2], 0.0f) * sW[4*q+2];
            acc += fmaxf(a.w + di2 * xv.w + sb[4*q+3], 0.0f) * sW[4*q+3];
        }
        xw3[i] = acc;
    }
}

// out[dst] += dinv[src]*dinv[dst] * xw3[src]
__global__ void k_scatter1(const int* __restrict__ src, const int* __restrict__ dst,
                           const float* __restrict__ dinv, const float* __restrict__ xw3,
                           float* __restrict__ out, int E) {
    int i = blockIdx.x * blockDim.x + threadIdx.x;
    int stride = gridDim.x * blockDim.x;
    for (; i < E; i += stride) {
        int s = src[i], d = dst[i];
        atomicAdd(&out[d], dinv[s] * dinv[d] * xw3[s]);
    }
}

// out += dinv^2 * xw3 + b3
__global__ void k_final(const float* __restrict__ xw3, const float* __restrict__ dinv,
                        const float* __restrict__ b3, float* __restrict__ out, int n) {
    int i = blockIdx.x * blockDim.x + threadIdx.x;
    int stride = gridDim.x * blockDim.x;
    for (; i < n; i += stride) out[i] += dinv[i] * dinv[i] * xw3[i] + b3[0];
}

extern "C" void kernel_launch(void* const* d_in, const int* in_sizes, int n_in,
                              void* d_out, int out_size, void* d_ws, size_t ws_size,
                              hipStream_t stream) {
    const float* x  = (const float*)d_in[0];
    const int*   ei = (const int*)d_in[1];
    const float* W1 = (const float*)d_in[2];
    const float* b1 = (const float*)d_in[3];
    const float* W2 = (const float*)d_in[4];
    const float* b2 = (const float*)d_in[5];
    const float* W3 = (const float*)d_in[6];
    const float* b3 = (const float*)d_in[7];

    const int n = in_sizes[0] / 2;   // [n, 2] features
    const int E = in_sizes[1] / 2;   // [2, E] edge index
    const int* src = ei;
    const int* dst = ei + E;

    float* ws   = (float*)d_ws;
    float* dinv = ws;                          // n      (deg, then dinv in-place)
    float* xw   = ws + n;                      // n*16   (xw1, then xw2 in-place)
    float* agg  = ws + n + (size_t)n * F;      // n*16
    float* xw3  = ws + n + (size_t)n * 2 * F;  // n
    float* out  = (float*)d_out;

    const int blk = 256;
    const int gridN = (n + blk - 1) / blk;            // 977 blocks
    const int gridE = 4096;                           // grid-stride over 4M edges
    const int gridS = 8192;                           // grid-stride over 64M (edge,feat)

    // degree / normalization (edge-structure only, reused by all layers)
    k_deg_init<<<gridN, blk, 0, stream>>>(dinv, n);
    k_deg_accum<<<gridE, blk, 0, stream>>>(dst, dinv, E);
    k_dinv<<<gridN, blk, 0, stream>>>(dinv, n);

    // layer 1
    k_l1_transform<<<gridN, blk, 0, stream>>>(x, W1, xw, n);
    hipMemsetAsync(agg, 0, (size_t)n * F * sizeof(float), stream);
    k_scatter16<<<gridS, blk, 0, stream>>>(src, dst, dinv, xw, agg, E);
    k_finish_transform16<<<gridN, blk, 0, stream>>>(agg, dinv, b1, W2, xw, n);  // xw -> xw2

    // layer 2
    hipMemsetAsync(agg, 0, (size_t)n * F * sizeof(float), stream);
    k_scatter16<<<gridS, blk, 0, stream>>>(src, dst, dinv, xw, agg, E);
    k_finish_transform1<<<gridN, blk, 0, stream>>>(agg, dinv, b2, W3, xw, xw3, n);

    // layer 3 (scalar): scatter straight into d_out
    hipMemsetAsync(out, 0, (size_t)n * sizeof(float), stream);
    k_scatter1<<<gridE, blk, 0, stream>>>(src, dst, dinv, xw3, out, E);
    k_final<<<gridN, blk, 0, stream>>>(xw3, dinv, b3, out, n);
}

// Round 2
// 752.206 us; speedup vs baseline: 1.2284x; 1.2284x over previous
//
#include <hip/hip_runtime.h>

// 3-layer GCN 2->16->16->1, N=250k nodes, E=4M edges.
// Strategy: build CSR (edges grouped by dst) once per call, then every
// aggregation is a gather (no float atomics). Rows pre-scaled by dinv so
// agg = dinv[d] * sum(dxw[src]). Gather + relu + next dense transform fused.

constexpr int F = 16;

// ---- CSR build ------------------------------------------------------------

__global__ void k_hist(const int* __restrict__ dst, int* __restrict__ count, int E) {
    int i = blockIdx.x * blockDim.x + threadIdx.x;
    int stride = gridDim.x * blockDim.x;
    for (; i < E; i += stride) atomicAdd(&count[dst[i]], 1);
}

// Per-block exclusive scan of count; block base from a global atomic counter.
// Segments are contiguous per block (node order preserved inside a block),
// which is all the gather needs (start + len per node).
__global__ void k_assign(const int* __restrict__ count, int* __restrict__ row_start,
                         int* __restrict__ cursor, float* __restrict__ dinv,
                         int* __restrict__ gcounter, int n) {
    __shared__ int s[256];
    __shared__ int sbase;
    int tid = threadIdx.x;
    int i = blockIdx.x * 256 + tid;
    int c = (i < n) ? count[i] : 0;
    s[tid] = c;
    __syncthreads();
#pragma unroll
    for (int off = 1; off < 256; off <<= 1) {
        int t = (tid >= off) ? s[tid - off] : 0;
        __syncthreads();
        s[tid] += t;
        __syncthreads();
    }
    if (tid == 0) sbase = atomicAdd(gcounter, s[255]);
    __syncthreads();
    if (i < n) {
        int start = sbase + s[tid] - c;   // exclusive
        row_start[i] = start;
        cursor[i] = start;
        dinv[i] = rsqrtf((float)c + 1.0f);
    }
}

__global__ void k_fill(const int* __restrict__ src, const int* __restrict__ dst,
                       int* __restrict__ cursor, int* __restrict__ csr, int E) {
    int i = blockIdx.x * blockDim.x + threadIdx.x;
    int stride = gridDim.x * blockDim.x;
    for (; i < E; i += stride) {
        int p = atomicAdd(&cursor[dst[i]], 1);
        csr[p] = src[i];
    }
}

// ---- layer kernels --------------------------------------------------------

// dxw = dinv * (x @ W1)    x:[n,2] W1:[2,16]
__global__ void k_t1(const float* __restrict__ x, const float* __restrict__ W1,
                     const float* __restrict__ dinv, float* __restrict__ dxw, int n) {
    __shared__ float sW[32];
    if (threadIdx.x < 32) sW[threadIdx.x] = W1[threadIdx.x];
    __syncthreads();
    int i = blockIdx.x * blockDim.x + threadIdx.x;
    int stride = gridDim.x * blockDim.x;
    for (; i < n; i += stride) {
        float2 xv = reinterpret_cast<const float2*>(x)[i];
        float di = dinv[i];
        float4* orow = reinterpret_cast<float4*>(dxw + (size_t)i * F);
#pragma unroll
        for (int q = 0; q < 4; ++q) {
            float4 o;
            o.x = di * (xv.x * sW[4*q+0] + xv.y * sW[16 + 4*q+0]);
            o.y = di * (xv.x * sW[4*q+1] + xv.y * sW[16 + 4*q+1]);
            o.z = di * (xv.x * sW[4*q+2] + xv.y * sW[16 + 4*q+2]);
            o.w = di * (xv.x * sW[4*q+3] + xv.y * sW[16 + 4*q+3]);
            orow[q] = o;
        }
    }
}

// Fused: gather-sum dxw rows over in-edges, h = relu(dinv*(acc+dxw_self)+b),
// out_row = dinv * (h @ W)   — 16 lanes (quarter-wave) per node, lane = feature.
__global__ void k_layer16(const int* __restrict__ row_start, const int* __restrict__ count,
                          const int* __restrict__ csr, const float* __restrict__ dinv,
                          const float* __restrict__ dxw, const float* __restrict__ b,
                          const float* __restrict__ W, float* __restrict__ dxw_out, int n) {
    __shared__ float sW[256];
    __shared__ float sb[16];
    sW[threadIdx.x] = W[threadIdx.x];              // blockDim.x == 256
    if (threadIdx.x < 16) sb[threadIdx.x] = b[threadIdx.x];
    __syncthreads();
    int j = threadIdx.x & 15;
    int i = blockIdx.x * 16 + (threadIdx.x >> 4);
    if (i >= n) return;
    int start = row_start[i];
    int end = start + count[i];
    float acc = 0.0f;
    int k = start;
    for (; k + 1 < end; k += 2) {
        int s0 = csr[k], s1 = csr[k+1];
        acc += dxw[(size_t)s0 * F + j] + dxw[(size_t)s1 * F + j];
    }
    if (k < end) acc += dxw[(size_t)csr[k] * F + j];
    float di = dinv[i];
    float h = fmaxf(di * (acc + dxw[(size_t)i * F + j]) + sb[j], 0.0f);
    float o = 0.0f;
#pragma unroll
    for (int q = 0; q < 16; ++q) {
        float hq = __shfl(h, q, 16);
        o += hq * sW[q * 16 + j];
    }
    dxw_out[(size_t)i * F + j] = di * o;
}

// Same gather, but final transform is 16->1 (W3), output dxw3 = dinv*(h@W3).
__global__ void k_layer_last(const int* __restrict__ row_start, const int* __restrict__ count,
                             const int* __restrict__ csr, const float* __restrict__ dinv,
                             const float* __restrict__ dxw, const float* __restrict__ b,
                             const float* __restrict__ W3, float* __restrict__ dxw3, int n) {
    __shared__ float sW[16];
    __shared__ float sb[16];
    if (threadIdx.x < 16) { sW[threadIdx.x] = W3[threadIdx.x]; sb[threadIdx.x] = b[threadIdx.x]; }
    __syncthreads();
    int j = threadIdx.x & 15;
    int i = blockIdx.x * 16 + (threadIdx.x >> 4);
    if (i >= n) return;
    int start = row_start[i];
    int end = start + count[i];
    float acc = 0.0f;
    int k = start;
    for (; k + 1 < end; k += 2) {
        int s0 = csr[k], s1 = csr[k+1];
        acc += dxw[(size_t)s0 * F + j] + dxw[(size_t)s1 * F + j];
    }
    if (k < end) acc += dxw[(size_t)csr[k] * F + j];
    float di = dinv[i];
    float h = fmaxf(di * (acc + dxw[(size_t)i * F + j]) + sb[j], 0.0f);
    float r = h * sW[j];
    r += __shfl_xor(r, 1, 16);
    r += __shfl_xor(r, 2, 16);
    r += __shfl_xor(r, 4, 16);
    r += __shfl_xor(r, 8, 16);
    if (j == 0) dxw3[i] = di * r;
}

// out[i] = dinv[i] * (sum dxw3[csr] + dxw3[i]) + b3 — 16 lanes per node over edges.
__global__ void k_out(const int* __restrict__ row_start, const int* __restrict__ count,
                      const int* __restrict__ csr, const float* __restrict__ dinv,
                      const float* __restrict__ dxw3, const float* __restrict__ b3,
                      float* __restrict__ out, int n) {
    int j = threadIdx.x & 15;
    int i = blockIdx.x * 16 + (threadIdx.x >> 4);
    if (i >= n) return;
    int start = row_start[i];
    int len = count[i];
    float acc = 0.0f;
    for (int k = j; k < len; k += 16) acc += dxw3[csr[start + k]];
    acc += __shfl_xor(acc, 1, 16);
    acc += __shfl_xor(acc, 2, 16);
    acc += __shfl_xor(acc, 4, 16);
    acc += __shfl_xor(acc, 8, 16);
    if (j == 0) out[i] = dinv[i] * (acc + dxw3[i]) + b3[0];
}

// ---- launch ---------------------------------------------------------------

extern "C" void kernel_launch(void* const* d_in, const int* in_sizes, int n_in,
                              void* d_out, int out_size, void* d_ws, size_t ws_size,
                              hipStream_t stream) {
    const float* x  = (const float*)d_in[0];
    const int*   ei = (const int*)d_in[1];
    const float* W1 = (const float*)d_in[2];
    const float* b1 = (const float*)d_in[3];
    const float* W2 = (const float*)d_in[4];
    const float* b2 = (const float*)d_in[5];
    const float* W3 = (const float*)d_in[6];
    const float* b3 = (const float*)d_in[7];

    const int n = in_sizes[0] / 2;   // [n,2]
    const int E = in_sizes[1] / 2;   // [2,E]
    const int* src = ei;
    const int* dst = ei + E;

    // workspace layout (n divisible by 4 so all blocks stay 16B aligned)
    char* w = (char*)d_ws;
    int*   count     = (int*)w;                 w += (size_t)n * 4;
    int*   row_start = (int*)w;                 w += (size_t)n * 4;
    int*   cursor    = (int*)w;                 w += (size_t)n * 4;
    int*   gcounter  = (int*)w;                 w += 16;           // padded
    float* dinv      = (float*)w;               w += (size_t)n * 4;
    int*   csr       = (int*)w;                 w += (size_t)E * 4;
    float* dxw       = (float*)w;               w += (size_t)n * F * 4;
    float* dxw2      = (float*)w;               w += (size_t)n * F * 4;
    float* dxw3      = (float*)w;               w += (size_t)n * 4;
    float* out       = (float*)d_out;

    const int blk = 256;
    const int gridN  = (n + blk - 1) / blk;       // 977
    const int gridE  = 8192;                      // grid-stride over 4M edges
    const int grid16 = (n + 15) / 16;             // 15625 (16 nodes / block)

    // CSR build
    hipMemsetAsync(count, 0, (size_t)n * 4, stream);
    hipMemsetAsync(gcounter, 0, 4, stream);
    k_hist<<<gridE, blk, 0, stream>>>(dst, count, E);
    k_assign<<<gridN, blk, 0, stream>>>(count, row_start, cursor, dinv, gcounter, n);
    k_fill<<<gridE, blk, 0, stream>>>(src, dst, cursor, csr, E);

    // layers
    k_t1<<<gridN, blk, 0, stream>>>(x, W1, dinv, dxw, n);
    k_layer16<<<grid16, blk, 0, stream>>>(row_start, count, csr, dinv, dxw, b1, W2, dxw2, n);
    k_layer_last<<<grid16, blk, 0, stream>>>(row_start, count, csr, dinv, dxw2, b2, W3, dxw3, n);
    k_out<<<grid16, blk, 0, stream>>>(row_start, count, csr, dinv, dxw3, b3, out, n);
}

// Round 3
// 666.077 us; speedup vs baseline: 1.3872x; 1.1293x over previous
//
#include <hip/hip_runtime.h>

// 3-layer GCN 2->16->16->1, N=250k nodes, E=4M edges.
// CSR (grouped by dst) built once per call; aggregations are gathers.
// k_fill is windowed by dst-range so scattered csr writes stay L2-resident
// and merge into full lines before eviction.

constexpr int F = 16;

// ---- CSR build ------------------------------------------------------------

__global__ void k_hist(const int* __restrict__ dst, int* __restrict__ count, int E) {
    int i = blockIdx.x * blockDim.x + threadIdx.x;
    int stride = gridDim.x * blockDim.x;
    for (; i < E; i += stride) atomicAdd(&count[dst[i]], 1);
}

// Per-block exclusive scan of count; block base from a global atomic counter.
__global__ void k_assign(const int* __restrict__ count, int* __restrict__ row_start,
                         int* __restrict__ cursor, float* __restrict__ dinv,
                         int* __restrict__ gcounter, int n) {
    __shared__ int s[256];
    __shared__ int sbase;
    int tid = threadIdx.x;
    int i = blockIdx.x * 256 + tid;
    int c = (i < n) ? count[i] : 0;
    s[tid] = c;
    __syncthreads();
#pragma unroll
    for (int off = 1; off < 256; off <<= 1) {
        int t = (tid >= off) ? s[tid - off] : 0;
        __syncthreads();
        s[tid] += t;
        __syncthreads();
    }
    if (tid == 0) sbase = atomicAdd(gcounter, s[255]);
    __syncthreads();
    if (i < n) {
        int start = sbase + s[tid] - c;   // exclusive
        row_start[i] = start;
        cursor[i] = start;
        dinv[i] = rsqrtf((float)c + 1.0f);
    }
}

// Windowed fill: pass w only handles dst in [w*npw, (w+1)*npw). The csr slice
// touched per pass is ~2MB -> L2-resident -> partial writes merge before
// eviction. Windows are disjoint, so no inter-pass sync is needed.
__global__ void k_fill(const int* __restrict__ src, const int* __restrict__ dst,
                       int* __restrict__ cursor, int* __restrict__ csr, int E,
                       int npw, int nwin) {
    int tid0 = blockIdx.x * blockDim.x + threadIdx.x;
    int stride = gridDim.x * blockDim.x;
    for (int w = 0; w < nwin; ++w) {
        int lo = w * npw;
        int hi = lo + npw;
        for (int i = tid0; i < E; i += stride) {
            int d = dst[i];
            int s = src[i];
            if (d >= lo && d < hi) {
                int p = atomicAdd(&cursor[d], 1);
                csr[p] = s;
            }
        }
    }
}

// ---- layer kernels --------------------------------------------------------

// dxw = dinv * (x @ W1)    x:[n,2] W1:[2,16]
__global__ void k_t1(const float* __restrict__ x, const float* __restrict__ W1,
                     const float* __restrict__ dinv, float* __restrict__ dxw, int n) {
    __shared__ float sW[32];
    if (threadIdx.x < 32) sW[threadIdx.x] = W1[threadIdx.x];
    __syncthreads();
    int i = blockIdx.x * blockDim.x + threadIdx.x;
    int stride = gridDim.x * blockDim.x;
    for (; i < n; i += stride) {
        float2 xv = reinterpret_cast<const float2*>(x)[i];
        float di = dinv[i];
        float4* orow = reinterpret_cast<float4*>(dxw + (size_t)i * F);
#pragma unroll
        for (int q = 0; q < 4; ++q) {
            float4 o;
            o.x = di * (xv.x * sW[4*q+0] + xv.y * sW[16 + 4*q+0]);
            o.y = di * (xv.x * sW[4*q+1] + xv.y * sW[16 + 4*q+1]);
            o.z = di * (xv.x * sW[4*q+2] + xv.y * sW[16 + 4*q+2]);
            o.w = di * (xv.x * sW[4*q+3] + xv.y * sW[16 + 4*q+3]);
            orow[q] = o;
        }
    }
}

// Fused: gather-sum dxw rows over in-edges, h = relu(dinv*(acc+dxw_self)+b),
// out_row = dinv * (h @ W)  — 16 lanes per node, lane = feature.
__global__ void k_layer16(const int* __restrict__ row_start, const int* __restrict__ count,
                          const int* __restrict__ csr, const float* __restrict__ dinv,
                          const float* __restrict__ dxw, const float* __restrict__ b,
                          const float* __restrict__ W, float* __restrict__ dxw_out, int n) {
    __shared__ float sW[256];
    __shared__ float sb[16];
    sW[threadIdx.x] = W[threadIdx.x];              // blockDim.x == 256
    if (threadIdx.x < 16) sb[threadIdx.x] = b[threadIdx.x];
    __syncthreads();
    int j = threadIdx.x & 15;
    int i = blockIdx.x * 16 + (threadIdx.x >> 4);
    if (i >= n) return;
    int start = row_start[i];
    int end = start + count[i];
    float acc = 0.0f;
    int k = start;
    for (; k + 3 < end; k += 4) {
        int s0 = csr[k], s1 = csr[k+1], s2 = csr[k+2], s3 = csr[k+3];
        acc += dxw[(size_t)s0 * F + j] + dxw[(size_t)s1 * F + j]
             + dxw[(size_t)s2 * F + j] + dxw[(size_t)s3 * F + j];
    }
    for (; k < end; ++k) acc += dxw[(size_t)csr[k] * F + j];
    float di = dinv[i];
    float h = fmaxf(di * (acc + dxw[(size_t)i * F + j]) + sb[j], 0.0f);
    float o = 0.0f;
#pragma unroll
    for (int q = 0; q < 16; ++q) {
        float hq = __shfl(h, q, 16);
        o += hq * sW[q * 16 + j];
    }
    dxw_out[(size_t)i * F + j] = di * o;
}

// Same gather, final transform 16->1 (W3): dxw3 = dinv*(h@W3).
__global__ void k_layer_last(const int* __restrict__ row_start, const int* __restrict__ count,
                             const int* __restrict__ csr, const float* __restrict__ dinv,
                             const float* __restrict__ dxw, const float* __restrict__ b,
                             const float* __restrict__ W3, float* __restrict__ dxw3, int n) {
    __shared__ float sW[16];
    __shared__ float sb[16];
    if (threadIdx.x < 16) { sW[threadIdx.x] = W3[threadIdx.x]; sb[threadIdx.x] = b[threadIdx.x]; }
    __syncthreads();
    int j = threadIdx.x & 15;
    int i = blockIdx.x * 16 + (threadIdx.x >> 4);
    if (i >= n) return;
    int start = row_start[i];
    int end = start + count[i];
    float acc = 0.0f;
    int k = start;
    for (; k + 3 < end; k += 4) {
        int s0 = csr[k], s1 = csr[k+1], s2 = csr[k+2], s3 = csr[k+3];
        acc += dxw[(size_t)s0 * F + j] + dxw[(size_t)s1 * F + j]
             + dxw[(size_t)s2 * F + j] + dxw[(size_t)s3 * F + j];
    }
    for (; k < end; ++k) acc += dxw[(size_t)csr[k] * F + j];
    float di = dinv[i];
    float h = fmaxf(di * (acc + dxw[(size_t)i * F + j]) + sb[j], 0.0f);
    float r = h * sW[j];
    r += __shfl_xor(r, 1, 16);
    r += __shfl_xor(r, 2, 16);
    r += __shfl_xor(r, 4, 16);
    r += __shfl_xor(r, 8, 16);
    if (j == 0) dxw3[i] = di * r;
}

// out[i] = dinv[i] * (sum dxw3[csr] + dxw3[i]) + b3 — 16 lanes per node.
__global__ void k_out(const int* __restrict__ row_start, const int* __restrict__ count,
                      const int* __restrict__ csr, const float* __restrict__ dinv,
                      const float* __restrict__ dxw3, const float* __restrict__ b3,
                      float* __restrict__ out, int n) {
    int j = threadIdx.x & 15;
    int i = blockIdx.x * 16 + (threadIdx.x >> 4);
    if (i >= n) return;
    int start = row_start[i];
    int len = count[i];
    float acc = 0.0f;
    for (int k = j; k < len; k += 16) acc += dxw3[csr[start + k]];
    acc += __shfl_xor(acc, 1, 16);
    acc += __shfl_xor(acc, 2, 16);
    acc += __shfl_xor(acc, 4, 16);
    acc += __shfl_xor(acc, 8, 16);
    if (j == 0) out[i] = dinv[i] * (acc + dxw3[i]) + b3[0];
}

// ---- launch ---------------------------------------------------------------

extern "C" void kernel_launch(void* const* d_in, const int* in_sizes, int n_in,
                              void* d_out, int out_size, void* d_ws, size_t ws_size,
                              hipStream_t stream) {
    const float* x  = (const float*)d_in[0];
    const int*   ei = (const int*)d_in[1];
    const float* W1 = (const float*)d_in[2];
    const float* b1 = (const float*)d_in[3];
    const float* W2 = (const float*)d_in[4];
    const float* b2 = (const float*)d_in[5];
    const float* W3 = (const float*)d_in[6];
    const float* b3 = (const float*)d_in[7];

    const int n = in_sizes[0] / 2;   // [n,2]
    const int E = in_sizes[1] / 2;   // [2,E]
    const int* src = ei;
    const int* dst = ei + E;

    char* w = (char*)d_ws;
    int*   count     = (int*)w;                 w += (size_t)n * 4;
    int*   row_start = (int*)w;                 w += (size_t)n * 4;
    int*   cursor    = (int*)w;                 w += (size_t)n * 4;
    int*   gcounter  = (int*)w;                 w += 16;
    float* dinv      = (float*)w;               w += (size_t)n * 4;
    int*   csr       = (int*)w;                 w += (size_t)E * 4;
    float* dxw       = (float*)w;               w += (size_t)n * F * 4;
    float* dxw2      = (float*)w;               w += (size_t)n * F * 4;
    float* dxw3      = (float*)w;               w += (size_t)n * 4;
    float* out       = (float*)d_out;

    const int blk = 256;
    const int gridN  = (n + blk - 1) / blk;       // 977
    const int gridE  = 8192;                      // grid-stride over 4M edges
    const int grid16 = (n + 15) / 16;             // 15625

    // window size: ~31250 nodes -> ~2MB csr slice per pass (L2-resident)
    const int nwin = 8;
    const int npw  = (n + nwin - 1) / nwin;

    // CSR build
    hipMemsetAsync(count, 0, (size_t)n * 4, stream);
    hipMemsetAsync(gcounter, 0, 4, stream);
    k_hist<<<gridE, blk, 0, stream>>>(dst, count, E);
    k_assign<<<gridN, blk, 0, stream>>>(count, row_start, cursor, dinv, gcounter, n);
    k_fill<<<gridE, blk, 0, stream>>>(src, dst, cursor, csr, E, npw, nwin);

    // layers
    k_t1<<<gridN, blk, 0, stream>>>(x, W1, dinv, dxw, n);
    k_layer16<<<grid16, blk, 0, stream>>>(row_start, count, csr, dinv, dxw, b1, W2, dxw2, n);
    k_layer_last<<<grid16, blk, 0, stream>>>(row_start, count, csr, dinv, dxw2, b2, W3, dxw3, n);
    k_out<<<grid16, blk, 0, stream>>>(row_start, count, csr, dinv, dxw3, b3, out, n);
}

// Round 4
// 578.344 us; speedup vs baseline: 1.5976x; 1.1517x over previous
//
#include <hip/hip_runtime.h>

// 3-layer GCN 2->16->16->1, N=250k nodes, E=4M edges.
// CSR (grouped by dst) built once per call; aggregations are gathers.
// k_fill: window-per-XCD (blockIdx&7) so each csr line is written by ONE
// XCD's L2 -> partial stores merge into full lines before eviction.

constexpr int F = 16;

// ---- CSR build ------------------------------------------------------------

__global__ void k_hist(const int* __restrict__ dst, int* __restrict__ count, int E) {
    int i = blockIdx.x * blockDim.x + threadIdx.x;
    int stride = gridDim.x * blockDim.x;
    for (; i < E; i += stride) atomicAdd(&count[dst[i]], 1);
}

// Per-block exclusive scan of count; block base from a global atomic counter.
__global__ void k_assign(const int* __restrict__ count, int* __restrict__ row_start,
                         int* __restrict__ cursor, float* __restrict__ dinv,
                         int* __restrict__ gcounter, int n) {
    __shared__ int s[256];
    __shared__ int sbase;
    int tid = threadIdx.x;
    int i = blockIdx.x * 256 + tid;
    int c = (i < n) ? count[i] : 0;
    s[tid] = c;
    __syncthreads();
#pragma unroll
    for (int off = 1; off < 256; off <<= 1) {
        int t = (tid >= off) ? s[tid - off] : 0;
        __syncthreads();
        s[tid] += t;
        __syncthreads();
    }
    if (tid == 0) sbase = atomicAdd(gcounter, s[255]);
    __syncthreads();
    if (i < n) {
        int start = sbase + s[tid] - c;   // exclusive
        row_start[i] = start;
        cursor[i] = start;
        dinv[i] = rsqrtf((float)c + 1.0f);
    }
}

// All 8 windows concurrent; window chosen by blockIdx&7 (round-robins to one
// XCD each on MI355X). Each window's ~2MB csr slice is then written by a
// single XCD L2, merging partial stores. Correct under ANY block->XCD
// mapping; the &7 choice only affects locality.
__global__ void k_fill(const int* __restrict__ src, const int* __restrict__ dst,
                       int* __restrict__ cursor, int* __restrict__ csr, int E,
                       int npw) {
    int w = blockIdx.x & 7;
    int lo = w * npw;
    int hi = lo + npw;
    int tid = (int)(blockIdx.x >> 3) * blockDim.x + threadIdx.x;
    int stride = (int)(gridDim.x >> 3) * blockDim.x;
    for (int i = tid; i < E; i += stride) {
        int d = dst[i];
        if (d >= lo && d < hi) {
            int p = atomicAdd(&cursor[d], 1);
            csr[p] = src[i];
        }
    }
}

// ---- layer kernels --------------------------------------------------------

// dxw = dinv * (x @ W1)    x:[n,2] W1:[2,16]
__global__ void k_t1(const float* __restrict__ x, const float* __restrict__ W1,
                     const float* __restrict__ dinv, float* __restrict__ dxw, int n) {
    __shared__ float sW[32];
    if (threadIdx.x < 32) sW[threadIdx.x] = W1[threadIdx.x];
    __syncthreads();
    int i = blockIdx.x * blockDim.x + threadIdx.x;
    int stride = gridDim.x * blockDim.x;
    for (; i < n; i += stride) {
        float2 xv = reinterpret_cast<const float2*>(x)[i];
        float di = dinv[i];
        float4* orow = reinterpret_cast<float4*>(dxw + (size_t)i * F);
#pragma unroll
        for (int q = 0; q < 4; ++q) {
            float4 o;
            o.x = di * (xv.x * sW[4*q+0] + xv.y * sW[16 + 4*q+0]);
            o.y = di * (xv.x * sW[4*q+1] + xv.y * sW[16 + 4*q+1]);
            o.z = di * (xv.x * sW[4*q+2] + xv.y * sW[16 + 4*q+2]);
            o.w = di * (xv.x * sW[4*q+3] + xv.y * sW[16 + 4*q+3]);
            orow[q] = o;
        }
    }
}

// Fused: gather-sum dxw rows over in-edges, h = relu(dinv*(acc+dxw_self)+b),
// out_row = dinv * (h @ W)  — 16 lanes per node, lane = feature.
__global__ void k_layer16(const int* __restrict__ row_start, const int* __restrict__ count,
                          const int* __restrict__ csr, const float* __restrict__ dinv,
                          const float* __restrict__ dxw, const float* __restrict__ b,
                          const float* __restrict__ W, float* __restrict__ dxw_out, int n) {
    __shared__ float sW[256];
    __shared__ float sb[16];
    sW[threadIdx.x] = W[threadIdx.x];              // blockDim.x == 256
    if (threadIdx.x < 16) sb[threadIdx.x] = b[threadIdx.x];
    __syncthreads();
    int j = threadIdx.x & 15;
    int i = blockIdx.x * 16 + (threadIdx.x >> 4);
    if (i >= n) return;
    int start = row_start[i];
    int end = start + count[i];
    float acc = 0.0f;
    int k = start;
    for (; k + 3 < end; k += 4) {
        int s0 = csr[k], s1 = csr[k+1], s2 = csr[k+2], s3 = csr[k+3];
        acc += dxw[(size_t)s0 * F + j] + dxw[(size_t)s1 * F + j]
             + dxw[(size_t)s2 * F + j] + dxw[(size_t)s3 * F + j];
    }
    for (; k < end; ++k) acc += dxw[(size_t)csr[k] * F + j];
    float di = dinv[i];
    float h = fmaxf(di * (acc + dxw[(size_t)i * F + j]) + sb[j], 0.0f);
    float o = 0.0f;
#pragma unroll
    for (int q = 0; q < 16; ++q) {
        float hq = __shfl(h, q, 16);
        o += hq * sW[q * 16 + j];
    }
    dxw_out[(size_t)i * F + j] = di * o;
}

// Same gather, final transform 16->1 (W3): dxw3 = dinv*(h@W3).
__global__ void k_layer_last(const int* __restrict__ row_start, const int* __restrict__ count,
                             const int* __restrict__ csr, const float* __restrict__ dinv,
                             const float* __restrict__ dxw, const float* __restrict__ b,
                             const float* __restrict__ W3, float* __restrict__ dxw3, int n) {
    __shared__ float sW[16];
    __shared__ float sb[16];
    if (threadIdx.x < 16) { sW[threadIdx.x] = W3[threadIdx.x]; sb[threadIdx.x] = b[threadIdx.x]; }
    __syncthreads();
    int j = threadIdx.x & 15;
    int i = blockIdx.x * 16 + (threadIdx.x >> 4);
    if (i >= n) return;
    int start = row_start[i];
    int end = start + count[i];
    float acc = 0.0f;
    int k = start;
    for (; k + 3 < end; k += 4) {
        int s0 = csr[k], s1 = csr[k+1], s2 = csr[k+2], s3 = csr[k+3];
        acc += dxw[(size_t)s0 * F + j] + dxw[(size_t)s1 * F + j]
             + dxw[(size_t)s2 * F + j] + dxw[(size_t)s3 * F + j];
    }
    for (; k < end; ++k) acc += dxw[(size_t)csr[k] * F + j];
    float di = dinv[i];
    float h = fmaxf(di * (acc + dxw[(size_t)i * F + j]) + sb[j], 0.0f);
    float r = h * sW[j];
    r += __shfl_xor(r, 1, 16);
    r += __shfl_xor(r, 2, 16);
    r += __shfl_xor(r, 4, 16);
    r += __shfl_xor(r, 8, 16);
    if (j == 0) dxw3[i] = di * r;
}

// out[i] = dinv[i] * (sum dxw3[csr] + dxw3[i]) + b3 — 16 lanes per node.
__global__ void k_out(const int* __restrict__ row_start, const int* __restrict__ count,
                      const int* __restrict__ csr, const float* __restrict__ dinv,
                      const float* __restrict__ dxw3, const float* __restrict__ b3,
                      float* __restrict__ out, int n) {
    int j = threadIdx.x & 15;
    int i = blockIdx.x * 16 + (threadIdx.x >> 4);
    if (i >= n) return;
    int start = row_start[i];
    int len = count[i];
    float acc = 0.0f;
    for (int k = j; k < len; k += 16) acc += dxw3[csr[start + k]];
    acc += __shfl_xor(acc, 1, 16);
    acc += __shfl_xor(acc, 2, 16);
    acc += __shfl_xor(acc, 4, 16);
    acc += __shfl_xor(acc, 8, 16);
    if (j == 0) out[i] = dinv[i] * (acc + dxw3[i]) + b3[0];
}

// ---- launch ---------------------------------------------------------------

extern "C" void kernel_launch(void* const* d_in, const int* in_sizes, int n_in,
                              void* d_out, int out_size, void* d_ws, size_t ws_size,
                              hipStream_t stream) {
    const float* x  = (const float*)d_in[0];
    const int*   ei = (const int*)d_in[1];
    const float* W1 = (const float*)d_in[2];
    const float* b1 = (const float*)d_in[3];
    const float* W2 = (const float*)d_in[4];
    const float* b2 = (const float*)d_in[5];
    const float* W3 = (const float*)d_in[6];
    const float* b3 = (const float*)d_in[7];

    const int n = in_sizes[0] / 2;   // [n,2]
    const int E = in_sizes[1] / 2;   // [2,E]
    const int* src = ei;
    const int* dst = ei + E;

    char* w = (char*)d_ws;
    int*   count     = (int*)w;                 w += (size_t)n * 4;
    int*   row_start = (int*)w;                 w += (size_t)n * 4;
    int*   cursor    = (int*)w;                 w += (size_t)n * 4;
    int*   gcounter  = (int*)w;                 w += 16;
    float* dinv      = (float*)w;               w += (size_t)n * 4;
    int*   csr       = (int*)w;                 w += (size_t)E * 4;
    float* dxw       = (float*)w;               w += (size_t)n * F * 4;
    float* dxw2      = (float*)w;               w += (size_t)n * F * 4;
    float* dxw3      = (float*)w;               w += (size_t)n * 4;
    float* out       = (float*)d_out;

    const int blk = 256;
    const int gridN  = (n + blk - 1) / blk;       // 977
    const int gridE  = 8192;                      // grid-stride over 4M edges
    const int grid16 = (n + 15) / 16;             // 15625

    // 8 windows, one per XCD: ~31250 nodes -> ~2MB csr slice, fits one L2
    const int nwin = 8;
    const int npw  = (n + nwin - 1) / nwin;

    // CSR build
    hipMemsetAsync(count, 0, (size_t)n * 4, stream);
    hipMemsetAsync(gcounter, 0, 4, stream);
    k_hist<<<gridE, blk, 0, stream>>>(dst, count, E);
    k_assign<<<gridN, blk, 0, stream>>>(count, row_start, cursor, dinv, gcounter, n);
    k_fill<<<gridE, blk, 0, stream>>>(src, dst, cursor, csr, E, npw);

    // layers
    k_t1<<<gridN, blk, 0, stream>>>(x, W1, dinv, dxw, n);
    k_layer16<<<grid16, blk, 0, stream>>>(row_start, count, csr, dinv, dxw, b1, W2, dxw2, n);
    k_layer_last<<<grid16, blk, 0, stream>>>(row_start, count, csr, dinv, dxw2, b2, W3, dxw3, n);
    k_out<<<grid16, blk, 0, stream>>>(row_start, count, csr, dinv, dxw3, b3, out, n);
}

// Round 5
// 552.908 us; speedup vs baseline: 1.6711x; 1.0460x over previous
//
#include <hip/hip_runtime.h>

// 3-layer GCN 2->16->16->1, N=250k, E=4M.
// Two-pass exact binning by dst-bucket (256 nodes/bucket) with per-(block,
// bucket) private output regions (L2-resident -> full-line writes).
// Layers: one block per bucket, LDS float-atomic accumulator tile, fused
// relu + linear transform. Aggregation/transform commuted so layer1 gathers
// 2-wide rows (8B/edge) and layer3 scalars; only layer2 gathers 16-wide rows.
//
// Math: gcn(x) = dinv_d*(sum_src dinv_s*xw_s + dinv_d*xw_d) + b, xw = x@W.
// Since agg is linear, agg(x@W) = agg(x)@W: layer1 aggregates dx=dinv*x
// (2-wide) and applies W1 after; layer2 aggregates dh1=dinv*relu(L1) and
// applies W2+b2+relu+W3 after; layer3 aggregates scalar dxw3.

constexpr int K   = 977;   // ceil(250000/256) dst buckets
constexpr int NPW = 256;   // nodes per bucket (power of 2)
constexpr int G   = 256;   // binning blocks
constexpr int F   = 16;

// ---- binning ---------------------------------------------------------------

__global__ __launch_bounds__(1024) void k_bcount(const int* __restrict__ dst,
        int* __restrict__ bcount, int E, int chunk) {
    __shared__ int h[K];
    for (int k = threadIdx.x; k < K; k += 1024) h[k] = 0;
    __syncthreads();
    int beg = blockIdx.x * chunk;
    int end = min(beg + chunk, E);
    for (int i = beg + threadIdx.x; i < end; i += 1024) {
        int d = __builtin_nontemporal_load(&dst[i]);
        atomicAdd(&h[d >> 8], 1);
    }
    __syncthreads();
    for (int k = threadIdx.x; k < K; k += 1024)
        bcount[blockIdx.x * K + k] = h[k];   // block-major, coalesced
}

// Single block: column sums -> exclusive scan over buckets -> rewrite bcount
// in place as per-(block,bucket) exclusive bases.
__global__ __launch_bounds__(1024) void k_scan(int* __restrict__ bcount,
        int* __restrict__ colbase, int E) {
    __shared__ int tot[1024];
    int k = threadIdx.x;
    int s = 0;
    if (k < K) for (int b = 0; b < G; ++b) s += bcount[b * K + k];
    tot[k] = s;
    __syncthreads();
    for (int off = 1; off < 1024; off <<= 1) {
        int t = (k >= off) ? tot[k - off] : 0;
        __syncthreads();
        tot[k] += t;
        __syncthreads();
    }
    if (k < K) {
        int run = tot[k] - s;        // exclusive bucket base
        colbase[k] = run;
        for (int b = 0; b < G; ++b) {
            int t = bcount[b * K + k];
            bcount[b * K + k] = run;
            run += t;
        }
    }
    if (k == 0) colbase[K] = E;
}

// Fill: each block writes its own pre-reserved slots (LDS cursors seeded from
// per-(block,bucket) bases). Entry packs (src<<8)|local_dst.
__global__ __launch_bounds__(1024) void k_bfill(const int* __restrict__ src,
        const int* __restrict__ dst, const int* __restrict__ base,
        int* __restrict__ ent, int E, int chunk) {
    __shared__ int cur[K];
    for (int k = threadIdx.x; k < K; k += 1024)
        cur[k] = base[blockIdx.x * K + k];
    __syncthreads();
    int beg = blockIdx.x * chunk;
    int end = min(beg + chunk, E);
    for (int i = beg + threadIdx.x; i < end; i += 1024) {
        int d = __builtin_nontemporal_load(&dst[i]);
        int s = __builtin_nontemporal_load(&src[i]);
        int pos = atomicAdd(&cur[d >> 8], 1);
        ent[pos] = (s << 8) | (d & 255);
    }
}

// ---- per-bucket degree + pre-scaled 2-wide input ----------------------------

__global__ __launch_bounds__(256) void k_prep(const int* __restrict__ ent,
        const int* __restrict__ colbase, const float* __restrict__ x,
        float* __restrict__ dinv, float* __restrict__ dx, int n) {
    __shared__ int h[NPW];
    h[threadIdx.x] = 0;
    __syncthreads();
    int beg = colbase[blockIdx.x], end = colbase[blockIdx.x + 1];
    for (int e = beg + threadIdx.x; e < end; e += 256) {
        int v = __builtin_nontemporal_load(&ent[e]);
        atomicAdd(&h[v & 255], 1);
    }
    __syncthreads();
    int i = (blockIdx.x << 8) + threadIdx.x;
    if (i < n) {
        float di = rsqrtf((float)h[threadIdx.x] + 1.0f);
        dinv[i] = di;
        float2 xv = reinterpret_cast<const float2*>(x)[i];
        reinterpret_cast<float2*>(dx)[i] = make_float2(di * xv.x, di * xv.y);
    }
}

// ---- layer 1: aggregate 2-wide dx, then (2->16) W1 + b1 + relu -------------
// dh1[i] = dinv[i] * relu( [dinv[i]*(sum dx[src] + dx[i])] @ W1 + b1 )

__global__ __launch_bounds__(512) void k_layer1(const int* __restrict__ ent,
        const int* __restrict__ colbase, const float* __restrict__ dinv,
        const float* __restrict__ dx, const float* __restrict__ W1,
        const float* __restrict__ b1, float* __restrict__ dh1, int n) {
    __shared__ float acc[NPW * 2];
    __shared__ float sW[32];
    __shared__ float sb[16];
    if (threadIdx.x < 32) sW[threadIdx.x] = W1[threadIdx.x];
    if (threadIdx.x >= 32 && threadIdx.x < 48) sb[threadIdx.x - 32] = b1[threadIdx.x - 32];
    for (int t = threadIdx.x; t < NPW * 2; t += 512) acc[t] = 0.0f;
    __syncthreads();
    int beg = colbase[blockIdx.x], end = colbase[blockIdx.x + 1];
    for (int e = beg + threadIdx.x; e < end; e += 512) {
        int v = __builtin_nontemporal_load(&ent[e]);
        float2 xv = reinterpret_cast<const float2*>(dx)[v >> 8];
        int ld = v & 255;
        atomicAdd(&acc[ld * 2 + 0], xv.x);
        atomicAdd(&acc[ld * 2 + 1], xv.y);
    }
    __syncthreads();
    int r = threadIdx.x;
    if (r < NPW) {
        int i = (blockIdx.x << 8) + r;
        if (i < n) {
            float di = dinv[i];
            float2 ds = reinterpret_cast<const float2*>(dx)[i];
            float a0 = di * (acc[r * 2 + 0] + ds.x);
            float a1 = di * (acc[r * 2 + 1] + ds.y);
            float4* orow = reinterpret_cast<float4*>(dh1 + (size_t)i * F);
#pragma unroll
            for (int q = 0; q < 4; ++q) {
                float4 o;
                o.x = di * fmaxf(a0 * sW[4*q+0] + a1 * sW[16 + 4*q+0] + sb[4*q+0], 0.0f);
                o.y = di * fmaxf(a0 * sW[4*q+1] + a1 * sW[16 + 4*q+1] + sb[4*q+1], 0.0f);
                o.z = di * fmaxf(a0 * sW[4*q+2] + a1 * sW[16 + 4*q+2] + sb[4*q+2], 0.0f);
                o.w = di * fmaxf(a0 * sW[4*q+3] + a1 * sW[16 + 4*q+3] + sb[4*q+3], 0.0f);
                orow[q] = o;
            }
        }
    }
}

// ---- layer 2: aggregate 16-wide dh1; h2 = relu(agg@W2 + b2); dxw3 = di*(h2.W3)

__global__ __launch_bounds__(512) void k_layer2(const int* __restrict__ ent,
        const int* __restrict__ colbase, const float* __restrict__ dinv,
        const float* __restrict__ dh1, const float* __restrict__ W2,
        const float* __restrict__ b2, const float* __restrict__ W3,
        float* __restrict__ dxw3, int n) {
    __shared__ float acc[NPW * 17];     // stride 17 to spread LDS banks
    __shared__ float sW2[256];
    __shared__ float sW3[16];
    __shared__ float sb[16];
    if (threadIdx.x < 256) sW2[threadIdx.x] = W2[threadIdx.x];
    if (threadIdx.x >= 256 && threadIdx.x < 272) sW3[threadIdx.x - 256] = W3[threadIdx.x - 256];
    if (threadIdx.x >= 272 && threadIdx.x < 288) sb[threadIdx.x - 272] = b2[threadIdx.x - 272];
    for (int t = threadIdx.x; t < NPW * 17; t += 512) acc[t] = 0.0f;
    __syncthreads();
    int beg = colbase[blockIdx.x], end = colbase[blockIdx.x + 1];
    int g = threadIdx.x >> 4;          // 32 groups of 16 lanes; lane = feature
    int j = threadIdx.x & 15;
    for (int e = beg + g; e < end; e += 32) {
        int v = __builtin_nontemporal_load(&ent[e]);   // broadcast within group
        int s = v >> 8, ld = v & 255;
        atomicAdd(&acc[ld * 17 + j], dh1[(size_t)s * F + j]);
    }
    __syncthreads();
    int r = threadIdx.x;
    if (r < NPW) {
        int i = (blockIdx.x << 8) + r;
        if (i < n) {
            float di = dinv[i];
            const float* dh = dh1 + (size_t)i * F;
            float a[16];
#pragma unroll
            for (int q = 0; q < 16; ++q) a[q] = di * (acc[r * 17 + q] + dh[q]);
            float sum = 0.0f;
#pragma unroll
            for (int c = 0; c < 16; ++c) {      // output feature c of layer2
                float h = sb[c];
#pragma unroll
                for (int q = 0; q < 16; ++q) h += a[q] * sW2[q * 16 + c];
                sum += fmaxf(h, 0.0f) * sW3[c];
            }
            dxw3[i] = di * sum;
        }
    }
}

// ---- layer 3 aggregation (scalar) -> out ------------------------------------

__global__ __launch_bounds__(512) void k_out(const int* __restrict__ ent,
        const int* __restrict__ colbase, const float* __restrict__ dinv,
        const float* __restrict__ dxw3, const float* __restrict__ b3,
        float* __restrict__ out, int n) {
    __shared__ float acc[NPW];
    for (int t = threadIdx.x; t < NPW; t += 512) acc[t] = 0.0f;
    __syncthreads();
    int beg = colbase[blockIdx.x], end = colbase[blockIdx.x + 1];
    for (int e = beg + threadIdx.x; e < end; e += 512) {
        int v = __builtin_nontemporal_load(&ent[e]);
        atomicAdd(&acc[v & 255], dxw3[v >> 8]);
    }
    __syncthreads();
    int r = threadIdx.x;
    if (r < NPW) {
        int i = (blockIdx.x << 8) + r;
        if (i < n) out[i] = dinv[i] * (acc[r] + dxw3[i]) + b3[0];
    }
}

// ---- launch -----------------------------------------------------------------

extern "C" void kernel_launch(void* const* d_in, const int* in_sizes, int n_in,
                              void* d_out, int out_size, void* d_ws, size_t ws_size,
                              hipStream_t stream) {
    const float* x  = (const float*)d_in[0];
    const int*   ei = (const int*)d_in[1];
    const float* W1 = (const float*)d_in[2];
    const float* b1 = (const float*)d_in[3];
    const float* W2 = (const float*)d_in[4];
    const float* b2 = (const float*)d_in[5];
    const float* W3 = (const float*)d_in[6];
    const float* b3 = (const float*)d_in[7];

    const int n = in_sizes[0] / 2;   // [n,2]
    const int E = in_sizes[1] / 2;   // [2,E]
    const int* src = ei;
    const int* dst = ei + E;

    char* w = (char*)d_ws;
    int*   ent     = (int*)w;                    w += (size_t)E * 4;          // 16MB
    int*   bcount  = (int*)w;                    w += (size_t)G * K * 4;      // ~1MB
    float* dinv    = (float*)w;                  w += (size_t)n * 4;          // 1MB
    float* dx      = (float*)w;                  w += (size_t)n * 2 * 4;      // 2MB
    float* dh1     = (float*)w;                  w += (size_t)n * F * 4;      // 16MB
    float* dxw3    = (float*)w;                  w += (size_t)n * 4;          // 1MB
    int*   colbase = (int*)w;                    w += (size_t)(K + 1) * 4;
    float* out     = (float*)d_out;

    const int chunk = (E + G - 1) / G;

    // binning (replaces hist/assign/fill; no memsets needed anywhere)
    k_bcount<<<G, 1024, 0, stream>>>(dst, bcount, E, chunk);
    k_scan  <<<1, 1024, 0, stream>>>(bcount, colbase, E);
    k_bfill <<<G, 1024, 0, stream>>>(src, dst, bcount, ent, E, chunk);

    // degree + pre-scaled input
    k_prep<<<K, 256, 0, stream>>>(ent, colbase, x, dinv, dx, n);

    // layers
    k_layer1<<<K, 512, 0, stream>>>(ent, colbase, dinv, dx, W1, b1, dh1, n);
    k_layer2<<<K, 512, 0, stream>>>(ent, colbase, dinv, dh1, W2, b2, W3, dxw3, n);
    k_out   <<<K, 512, 0, stream>>>(ent, colbase, dinv, dxw3, b3, out, n);
}

// Round 6
// 544.050 us; speedup vs baseline: 1.6984x; 1.0163x over previous
//
#include <hip/hip_runtime.h>

// 3-layer GCN 2->16->16->1, N=250k, E=4M.
// Two-pass exact binning by dst-bucket (256 nodes/bucket); layers are
// one-block-per-bucket with LDS accumulator tiles.
// R6: k_layer2 rewritten for memory-level parallelism — 4 lanes/edge
// (float4 quarter-rows) and 2-edge unroll -> 32 row-loads in flight per wave
// (was 4). The gather is latency-bound, not bandwidth-bound.

constexpr int K   = 977;   // ceil(250000/256) dst buckets
constexpr int NPW = 256;   // nodes per bucket
constexpr int G   = 256;   // binning blocks
constexpr int F   = 16;

// ---- binning ---------------------------------------------------------------

__global__ __launch_bounds__(1024) void k_bcount(const int* __restrict__ dst,
        int* __restrict__ bcount, int E, int chunk) {
    __shared__ int h[K];
    for (int k = threadIdx.x; k < K; k += 1024) h[k] = 0;
    __syncthreads();
    int beg = blockIdx.x * chunk;
    int end = min(beg + chunk, E);
    for (int i = beg + threadIdx.x; i < end; i += 1024) {
        int d = __builtin_nontemporal_load(&dst[i]);
        atomicAdd(&h[d >> 8], 1);
    }
    __syncthreads();
    for (int k = threadIdx.x; k < K; k += 1024)
        bcount[blockIdx.x * K + k] = h[k];   // block-major, coalesced
}

// Single block: column sums -> exclusive scan over buckets -> rewrite bcount
// in place as per-(block,bucket) exclusive bases.
__global__ __launch_bounds__(1024) void k_scan(int* __restrict__ bcount,
        int* __restrict__ colbase, int E) {
    __shared__ int tot[1024];
    int k = threadIdx.x;
    int s = 0;
    if (k < K) for (int b = 0; b < G; ++b) s += bcount[b * K + k];
    tot[k] = s;
    __syncthreads();
    for (int off = 1; off < 1024; off <<= 1) {
        int t = (k >= off) ? tot[k - off] : 0;
        __syncthreads();
        tot[k] += t;
        __syncthreads();
    }
    if (k < K) {
        int run = tot[k] - s;        // exclusive bucket base
        colbase[k] = run;
        for (int b = 0; b < G; ++b) {
            int t = bcount[b * K + k];
            bcount[b * K + k] = run;
            run += t;
        }
    }
    if (k == 0) colbase[K] = E;
}

// Fill: each block writes its own pre-reserved slots (LDS cursors seeded from
// per-(block,bucket) bases). Entry packs (src<<8)|local_dst.
__global__ __launch_bounds__(1024) void k_bfill(const int* __restrict__ src,
        const int* __restrict__ dst, const int* __restrict__ base,
        int* __restrict__ ent, int E, int chunk) {
    __shared__ int cur[K];
    for (int k = threadIdx.x; k < K; k += 1024)
        cur[k] = base[blockIdx.x * K + k];
    __syncthreads();
    int beg = blockIdx.x * chunk;
    int end = min(beg + chunk, E);
    for (int i = beg + threadIdx.x; i < end; i += 1024) {
        int d = __builtin_nontemporal_load(&dst[i]);
        int s = __builtin_nontemporal_load(&src[i]);
        int pos = atomicAdd(&cur[d >> 8], 1);
        ent[pos] = (s << 8) | (d & 255);
    }
}

// ---- per-bucket degree + pre-scaled 2-wide input ----------------------------

__global__ __launch_bounds__(256) void k_prep(const int* __restrict__ ent,
        const int* __restrict__ colbase, const float* __restrict__ x,
        float* __restrict__ dinv, float* __restrict__ dx, int n) {
    __shared__ int h[NPW];
    h[threadIdx.x] = 0;
    __syncthreads();
    int beg = colbase[blockIdx.x], end = colbase[blockIdx.x + 1];
    for (int e = beg + threadIdx.x; e < end; e += 256) {
        int v = __builtin_nontemporal_load(&ent[e]);
        atomicAdd(&h[v & 255], 1);
    }
    __syncthreads();
    int i = (blockIdx.x << 8) + threadIdx.x;
    if (i < n) {
        float di = rsqrtf((float)h[threadIdx.x] + 1.0f);
        dinv[i] = di;
        float2 xv = reinterpret_cast<const float2*>(x)[i];
        reinterpret_cast<float2*>(dx)[i] = make_float2(di * xv.x, di * xv.y);
    }
}

// ---- layer 1: aggregate 2-wide dx, then (2->16) W1 + b1 + relu -------------
// dh1[i] = dinv[i] * relu( [dinv[i]*(sum dx[src] + dx[i])] @ W1 + b1 )

__global__ __launch_bounds__(512) void k_layer1(const int* __restrict__ ent,
        const int* __restrict__ colbase, const float* __restrict__ dinv,
        const float* __restrict__ dx, const float* __restrict__ W1,
        const float* __restrict__ b1, float* __restrict__ dh1, int n) {
    __shared__ float acc[NPW * 2];
    __shared__ float sW[32];
    __shared__ float sb[16];
    if (threadIdx.x < 32) sW[threadIdx.x] = W1[threadIdx.x];
    if (threadIdx.x >= 32 && threadIdx.x < 48) sb[threadIdx.x - 32] = b1[threadIdx.x - 32];
    for (int t = threadIdx.x; t < NPW * 2; t += 512) acc[t] = 0.0f;
    __syncthreads();
    int beg = colbase[blockIdx.x], end = colbase[blockIdx.x + 1];
    int e = beg + threadIdx.x;
    for (; e + 512 < end; e += 1024) {
        int v0 = __builtin_nontemporal_load(&ent[e]);
        int v1 = __builtin_nontemporal_load(&ent[e + 512]);
        float2 a0 = reinterpret_cast<const float2*>(dx)[v0 >> 8];
        float2 a1 = reinterpret_cast<const float2*>(dx)[v1 >> 8];
        atomicAdd(&acc[(v0 & 255) * 2 + 0], a0.x);
        atomicAdd(&acc[(v0 & 255) * 2 + 1], a0.y);
        atomicAdd(&acc[(v1 & 255) * 2 + 0], a1.x);
        atomicAdd(&acc[(v1 & 255) * 2 + 1], a1.y);
    }
    if (e < end) {
        int v = __builtin_nontemporal_load(&ent[e]);
        float2 a = reinterpret_cast<const float2*>(dx)[v >> 8];
        atomicAdd(&acc[(v & 255) * 2 + 0], a.x);
        atomicAdd(&acc[(v & 255) * 2 + 1], a.y);
    }
    __syncthreads();
    int r = threadIdx.x;
    if (r < NPW) {
        int i = (blockIdx.x << 8) + r;
        if (i < n) {
            float di = dinv[i];
            float2 ds = reinterpret_cast<const float2*>(dx)[i];
            float a0 = di * (acc[r * 2 + 0] + ds.x);
            float a1 = di * (acc[r * 2 + 1] + ds.y);
            float4* orow = reinterpret_cast<float4*>(dh1 + (size_t)i * F);
#pragma unroll
            for (int q = 0; q < 4; ++q) {
                float4 o;
                o.x = di * fmaxf(a0 * sW[4*q+0] + a1 * sW[16 + 4*q+0] + sb[4*q+0], 0.0f);
                o.y = di * fmaxf(a0 * sW[4*q+1] + a1 * sW[16 + 4*q+1] + sb[4*q+1], 0.0f);
                o.z = di * fmaxf(a0 * sW[4*q+2] + a1 * sW[16 + 4*q+2] + sb[4*q+2], 0.0f);
                o.w = di * fmaxf(a0 * sW[4*q+3] + a1 * sW[16 + 4*q+3] + sb[4*q+3], 0.0f);
                orow[q] = o;
            }
        }
    }
}

// ---- layer 2: aggregate 16-wide dh1; h2 = relu(agg@W2 + b2); dxw3 = di*(h2.W3)
// MLP layout: 4 lanes per edge (float4 quarter-row each), 2-edge unroll ->
// 32 independent row loads in flight per wave.

__global__ __launch_bounds__(512) void k_layer2(const int* __restrict__ ent,
        const int* __restrict__ colbase, const float* __restrict__ dinv,
        const float* __restrict__ dh1, const float* __restrict__ W2,
        const float* __restrict__ b2, const float* __restrict__ W3,
        float* __restrict__ dxw3, int n) {
    __shared__ float acc[NPW * 17];     // stride 17 to spread LDS banks
    __shared__ float sW2[256];
    __shared__ float sW3[16];
    __shared__ float sb[16];
    if (threadIdx.x < 256) sW2[threadIdx.x] = W2[threadIdx.x];
    if (threadIdx.x >= 256 && threadIdx.x < 272) sW3[threadIdx.x - 256] = W3[threadIdx.x - 256];
    if (threadIdx.x >= 272 && threadIdx.x < 288) sb[threadIdx.x - 272] = b2[threadIdx.x - 272];
    for (int t = threadIdx.x; t < NPW * 17; t += 512) acc[t] = 0.0f;
    __syncthreads();
    int beg = colbase[blockIdx.x], end = colbase[blockIdx.x + 1];
    int q4 = (threadIdx.x & 3) * 4;     // feature quad offset: 0,4,8,12
    int eg = threadIdx.x >> 2;          // 128 edge slots
    int e = beg + eg;
    for (; e + 128 < end; e += 256) {
        int v0 = __builtin_nontemporal_load(&ent[e]);
        int v1 = __builtin_nontemporal_load(&ent[e + 128]);
        float4 r0 = *reinterpret_cast<const float4*>(dh1 + (size_t)(v0 >> 8) * F + q4);
        float4 r1 = *reinterpret_cast<const float4*>(dh1 + (size_t)(v1 >> 8) * F + q4);
        int b0 = (v0 & 255) * 17 + q4;
        int b1_ = (v1 & 255) * 17 + q4;
        atomicAdd(&acc[b0 + 0], r0.x);
        atomicAdd(&acc[b0 + 1], r0.y);
        atomicAdd(&acc[b0 + 2], r0.z);
        atomicAdd(&acc[b0 + 3], r0.w);
        atomicAdd(&acc[b1_ + 0], r1.x);
        atomicAdd(&acc[b1_ + 1], r1.y);
        atomicAdd(&acc[b1_ + 2], r1.z);
        atomicAdd(&acc[b1_ + 3], r1.w);
    }
    if (e < end) {
        int v = __builtin_nontemporal_load(&ent[e]);
        float4 r = *reinterpret_cast<const float4*>(dh1 + (size_t)(v >> 8) * F + q4);
        int b0 = (v & 255) * 17 + q4;
        atomicAdd(&acc[b0 + 0], r.x);
        atomicAdd(&acc[b0 + 1], r.y);
        atomicAdd(&acc[b0 + 2], r.z);
        atomicAdd(&acc[b0 + 3], r.w);
    }
    __syncthreads();
    int r = threadIdx.x;
    if (r < NPW) {
        int i = (blockIdx.x << 8) + r;
        if (i < n) {
            float di = dinv[i];
            const float* dh = dh1 + (size_t)i * F;
            float a[16];
#pragma unroll
            for (int q = 0; q < 16; ++q) a[q] = di * (acc[r * 17 + q] + dh[q]);
            float sum = 0.0f;
#pragma unroll
            for (int c = 0; c < 16; ++c) {      // output feature c of layer2
                float h = sb[c];
#pragma unroll
                for (int q = 0; q < 16; ++q) h += a[q] * sW2[q * 16 + c];
                sum += fmaxf(h, 0.0f) * sW3[c];
            }
            dxw3[i] = di * sum;
        }
    }
}

// ---- layer 3 aggregation (scalar) -> out ------------------------------------

__global__ __launch_bounds__(512) void k_out(const int* __restrict__ ent,
        const int* __restrict__ colbase, const float* __restrict__ dinv,
        const float* __restrict__ dxw3, const float* __restrict__ b3,
        float* __restrict__ out, int n) {
    __shared__ float acc[NPW];
    for (int t = threadIdx.x; t < NPW; t += 512) acc[t] = 0.0f;
    __syncthreads();
    int beg = colbase[blockIdx.x], end = colbase[blockIdx.x + 1];
    int e = beg + threadIdx.x;
    for (; e + 512 < end; e += 1024) {
        int v0 = __builtin_nontemporal_load(&ent[e]);
        int v1 = __builtin_nontemporal_load(&ent[e + 512]);
        float s0 = dxw3[v0 >> 8];
        float s1 = dxw3[v1 >> 8];
        atomicAdd(&acc[v0 & 255], s0);
        atomicAdd(&acc[v1 & 255], s1);
    }
    if (e < end) {
        int v = __builtin_nontemporal_load(&ent[e]);
        atomicAdd(&acc[v & 255], dxw3[v >> 8]);
    }
    __syncthreads();
    int r = threadIdx.x;
    if (r < NPW) {
        int i = (blockIdx.x << 8) + r;
        if (i < n) out[i] = dinv[i] * (acc[r] + dxw3[i]) + b3[0];
    }
}

// ---- launch -----------------------------------------------------------------

extern "C" void kernel_launch(void* const* d_in, const int* in_sizes, int n_in,
                              void* d_out, int out_size, void* d_ws, size_t ws_size,
                              hipStream_t stream) {
    const float* x  = (const float*)d_in[0];
    const int*   ei = (const int*)d_in[1];
    const float* W1 = (const float*)d_in[2];
    const float* b1 = (const float*)d_in[3];
    const float* W2 = (const float*)d_in[4];
    const float* b2 = (const float*)d_in[5];
    const float* W3 = (const float*)d_in[6];
    const float* b3 = (const float*)d_in[7];

    const int n = in_sizes[0] / 2;   // [n,2]
    const int E = in_sizes[1] / 2;   // [2,E]
    const int* src = ei;
    const int* dst = ei + E;

    char* w = (char*)d_ws;
    int*   ent     = (int*)w;                    w += (size_t)E * 4;          // 16MB
    int*   bcount  = (int*)w;                    w += (size_t)G * K * 4;      // ~1MB
    float* dinv    = (float*)w;                  w += (size_t)n * 4;          // 1MB
    float* dx      = (float*)w;                  w += (size_t)n * 2 * 4;      // 2MB
    float* dh1     = (float*)w;                  w += (size_t)n * F * 4;      // 16MB
    float* dxw3    = (float*)w;                  w += (size_t)n * 4;          // 1MB
    int*   colbase = (int*)w;                    w += (size_t)(K + 1) * 4;
    float* out     = (float*)d_out;

    const int chunk = (E + G - 1) / G;

    // binning
    k_bcount<<<G, 1024, 0, stream>>>(dst, bcount, E, chunk);
    k_scan  <<<1, 1024, 0, stream>>>(bcount, colbase, E);
    k_bfill <<<G, 1024, 0, stream>>>(src, dst, bcount, ent, E, chunk);

    // degree + pre-scaled input
    k_prep<<<K, 256, 0, stream>>>(ent, colbase, x, dinv, dx, n);

    // layers
    k_layer1<<<K, 512, 0, stream>>>(ent, colbase, dinv, dx, W1, b1, dh1, n);
    k_layer2<<<K, 512, 0, stream>>>(ent, colbase, dinv, dh1, W2, b2, W3, dxw3, n);
    k_out   <<<K, 512, 0, stream>>>(ent, colbase, dinv, dxw3, b3, out, n);
}